// Round 1
// baseline (977.204 us; speedup 1.0000x reference)
//
#include <hip/hip_runtime.h>
#include <hip/hip_bf16.h>
#include <math.h>

// ODE Euler solver with teacher forcing.
// Key insight: teacher forcing (r>=0.5) resets the state to h[:,:,t], so the
// 63-step scan per batch decomposes into independent chains. One workgroup per
// chain start (b, t0); each chain runs its Euler steps sequentially with
// MFMA bf16 matmuls (z state kept as bf16 hi+lo for ~fp32-state accuracy).

using bf16x8 = __attribute__((ext_vector_type(8))) short;   // 8 bf16 (4 VGPRs)
using f32x4  = __attribute__((ext_vector_type(4))) float;   // 4 fp32 acc

constexpr int Bb = 64, Cc = 256, Tt = 64, Vv = 25, Hh = 512;
constexpr int TV = Tt * Vv;                 // 1600
constexpr int ZSTRIDE = 264;                // shorts per z row (256 + 8 pad -> bank shift 4)
constexpr int USTRIDE = 520;                // shorts per u row (512 + 8 pad -> bank shift 4)

__device__ __forceinline__ short f2bf(float x) {
  union { float f; unsigned u; } v; v.f = x;
  unsigned r = v.u + 0x7FFFu + ((v.u >> 16) & 1u);   // round-to-nearest-even
  return (short)(r >> 16);
}
__device__ __forceinline__ float bf2f(short b) {
  union { float f; unsigned u; } v;
  v.u = ((unsigned)(unsigned short)b) << 16;
  return v.f;
}

// ---- Prepack W1, W2 (fp32, row-major) into MFMA A-fragment order (bf16) ----
// A-frag layout (16x16x32): lane holds A[m = lane&15][k = (lane>>4)*8 + j], j=0..7.
// a1p: A = W1^T (M=H=512 -> 32 mtiles, K=C=256 -> 8 ktiles): idx ((kt*32+mt)*64+lane)*8+j
// a2p: A = W2^T (M=C=256 -> 16 mtiles, K=H=512 -> 16 ktiles): idx ((kt*16+mt)*64+lane)*8+j
__global__ void prepack_kernel(const float* __restrict__ W1,
                               const float* __restrict__ W2,
                               short* __restrict__ a1p,
                               short* __restrict__ a2p) {
  int idx = blockIdx.x * 256 + threadIdx.x;
  if (idx < 131072) {
    int j = idx & 7, lane = (idx >> 3) & 63, mt = (idx >> 9) & 31, kt = idx >> 14;
    int m = lane & 15, quad = lane >> 4;
    int h = mt * 16 + m;
    int c = kt * 32 + quad * 8 + j;
    a1p[idx] = f2bf(W1[c * Hh + h]);
  } else {
    int i2 = idx - 131072;
    int j = i2 & 7, lane = (i2 >> 3) & 63, mt = (i2 >> 9) & 15, kt = i2 >> 13;
    int m = lane & 15, quad = lane >> 4;
    int cm = mt * 16 + m;
    int hk = kt * 32 + quad * 8 + j;
    a2p[i2] = f2bf(W2[hk * Cc + cm]);
  }
}

// ---- Chain kernel: one block (256 threads, 4 waves) per chain start ----
__global__ __launch_bounds__(256, 2) void chain_kernel(
    const float* __restrict__ hsrc, const float* __restrict__ b1,
    const float* __restrict__ b2,   const float* __restrict__ tf,
    const short* __restrict__ a1p,  const short* __restrict__ a2p,
    float* __restrict__ out) {
  // z state (bf16 hi+lo) and u, in [v][k] layout (k contiguous) for B-fragments.
  __shared__ __align__(16) short z_hi[Vv * ZSTRIDE];
  __shared__ __align__(16) short z_lo[Vv * ZSTRIDE];
  __shared__ __align__(16) short u_hi[Vv * USTRIDE];

  const int bidx = blockIdx.x;
  const int b  = bidx & 63;
  const int t0 = bidx >> 6;              // 0..62
  // chain start iff t0==0 or teacher-forced at t0
  if (!(t0 == 0 || tf[t0 * Bb + b] >= 0.5f)) return;

  const int tid = threadIdx.x;

  // ---- init: z = h[b, :, t0, :]; also copy slice 0 of output if t0==0 ----
  {
    const int c = tid;                   // 256 threads, one channel each
    const float* src = hsrc + ((size_t)(b * Cc + c)) * TV + (size_t)t0 * Vv;
    float* dst0 = out + ((size_t)(b * Cc + c)) * TV;
    #pragma unroll
    for (int v = 0; v < Vv; v++) {
      float z = src[v];
      short zh = f2bf(z);
      z_hi[v * ZSTRIDE + c] = zh;
      z_lo[v * ZSTRIDE + c] = f2bf(z - bf2f(zh));
      if (t0 == 0) dst0[v] = z;
    }
  }
  __syncthreads();

  const int lane = tid & 63;
  const int wave = tid >> 6;
  const int m16  = lane & 15;
  const int quad = lane >> 4;
  const int v0   = m16;                                   // n-tile 0 column
  const int v1   = 16 + m16;                              // n-tile 1 column (may be >= 25)
  const int v1r  = (v1 > Vv - 1) ? (Vv - 1) : v1;         // clamped row for LDS reads

  int t = t0;
  for (;;) {
    // ================= mm1: u = tanh(W1^T z + b1) =================
    // wave handles m-tiles wave*8 .. wave*8+7 (h), 2 n-tiles (v)
    f32x4 acc1[8][2];
    #pragma unroll
    for (int i = 0; i < 8; i++) {
      acc1[i][0] = (f32x4){0.f, 0.f, 0.f, 0.f};
      acc1[i][1] = (f32x4){0.f, 0.f, 0.f, 0.f};
    }
    #pragma unroll
    for (int kt = 0; kt < 8; kt++) {
      bf16x8 af[8];
      const short* abase = a1p + ((size_t)((kt * 32 + wave * 8) * 64 + lane)) * 8;
      #pragma unroll
      for (int i = 0; i < 8; i++) af[i] = *(const bf16x8*)(abase + (size_t)i * 64 * 8);
      const int koff = kt * 32 + quad * 8;
      bf16x8 bh0 = *(const bf16x8*)(&z_hi[v0  * ZSTRIDE + koff]);
      bf16x8 bl0 = *(const bf16x8*)(&z_lo[v0  * ZSTRIDE + koff]);
      bf16x8 bh1 = *(const bf16x8*)(&z_hi[v1r * ZSTRIDE + koff]);
      bf16x8 bl1 = *(const bf16x8*)(&z_lo[v1r * ZSTRIDE + koff]);
      #pragma unroll
      for (int i = 0; i < 8; i++) {
        acc1[i][0] = __builtin_amdgcn_mfma_f32_16x16x32_bf16(af[i], bh0, acc1[i][0], 0, 0, 0);
        acc1[i][0] = __builtin_amdgcn_mfma_f32_16x16x32_bf16(af[i], bl0, acc1[i][0], 0, 0, 0);
        acc1[i][1] = __builtin_amdgcn_mfma_f32_16x16x32_bf16(af[i], bh1, acc1[i][1], 0, 0, 0);
        acc1[i][1] = __builtin_amdgcn_mfma_f32_16x16x32_bf16(af[i], bl1, acc1[i][1], 0, 0, 0);
      }
    }
    // epilogue: u = tanh(acc + b1) -> LDS (C/D layout: col v = lane&15, row h = quad*4+reg)
    #pragma unroll
    for (int i = 0; i < 8; i++) {
      const int hbase = (wave * 8 + i) * 16 + quad * 4;
      const float4 b1v = *(const float4*)(b1 + hbase);
      #pragma unroll
      for (int nt = 0; nt < 2; nt++) {
        const int v = nt ? v1 : v0;
        if (v < Vv) {
          short4 pk;
          pk.x = f2bf(tanhf(acc1[i][nt][0] + b1v.x));
          pk.y = f2bf(tanhf(acc1[i][nt][1] + b1v.y));
          pk.z = f2bf(tanhf(acc1[i][nt][2] + b1v.z));
          pk.w = f2bf(tanhf(acc1[i][nt][3] + b1v.w));
          *(short4*)(&u_hi[v * USTRIDE + hbase]) = pk;
        }
      }
    }
    __syncthreads();   // barrier A: u fully written before mm2 reads it

    // ================= mm2: z' = z + W2^T u + b2 =================
    // wave handles m-tiles wave*4 .. wave*4+3 (c), 2 n-tiles (v)
    f32x4 acc2[4][2];
    #pragma unroll
    for (int i = 0; i < 4; i++) {
      const int cbase = (wave * 4 + i) * 16 + quad * 4;
      const float4 b2v = *(const float4*)(b2 + cbase);
      #pragma unroll
      for (int nt = 0; nt < 2; nt++) {
        const int vr = nt ? v1r : v0;
        short4 zh = *(const short4*)(&z_hi[vr * ZSTRIDE + cbase]);
        short4 zl = *(const short4*)(&z_lo[vr * ZSTRIDE + cbase]);
        acc2[i][nt][0] = bf2f(zh.x) + bf2f(zl.x) + b2v.x;
        acc2[i][nt][1] = bf2f(zh.y) + bf2f(zl.y) + b2v.y;
        acc2[i][nt][2] = bf2f(zh.z) + bf2f(zl.z) + b2v.z;
        acc2[i][nt][3] = bf2f(zh.w) + bf2f(zl.w) + b2v.w;
      }
    }
    #pragma unroll
    for (int kt = 0; kt < 16; kt++) {
      bf16x8 af[4];
      const short* abase = a2p + ((size_t)((kt * 16 + wave * 4) * 64 + lane)) * 8;
      #pragma unroll
      for (int i = 0; i < 4; i++) af[i] = *(const bf16x8*)(abase + (size_t)i * 64 * 8);
      const int koff = kt * 32 + quad * 8;
      bf16x8 bu0 = *(const bf16x8*)(&u_hi[v0  * USTRIDE + koff]);
      bf16x8 bu1 = *(const bf16x8*)(&u_hi[v1r * USTRIDE + koff]);
      #pragma unroll
      for (int i = 0; i < 4; i++) {
        acc2[i][0] = __builtin_amdgcn_mfma_f32_16x16x32_bf16(af[i], bu0, acc2[i][0], 0, 0, 0);
        acc2[i][1] = __builtin_amdgcn_mfma_f32_16x16x32_bf16(af[i], bu1, acc2[i][1], 0, 0, 0);
      }
    }
    // epilogue: write z' to global out[b, c, t+1, v] and back to LDS state
    #pragma unroll
    for (int i = 0; i < 4; i++) {
      const int cbase = (wave * 4 + i) * 16 + quad * 4;
      #pragma unroll
      for (int nt = 0; nt < 2; nt++) {
        const int v = nt ? v1 : v0;
        if (v < Vv) {
          short4 zh4, zl4;
          float z0f = acc2[i][nt][0]; short h0 = f2bf(z0f); zh4.x = h0; zl4.x = f2bf(z0f - bf2f(h0));
          float z1f = acc2[i][nt][1]; short h1 = f2bf(z1f); zh4.y = h1; zl4.y = f2bf(z1f - bf2f(h1));
          float z2f = acc2[i][nt][2]; short h2 = f2bf(z2f); zh4.z = h2; zl4.z = f2bf(z2f - bf2f(h2));
          float z3f = acc2[i][nt][3]; short h3 = f2bf(z3f); zh4.w = h3; zl4.w = f2bf(z3f - bf2f(h3));
          *(short4*)(&z_hi[v * ZSTRIDE + cbase]) = zh4;
          *(short4*)(&z_lo[v * ZSTRIDE + cbase]) = zl4;
          float* dst = out + ((size_t)(b * Cc + cbase)) * TV + (size_t)(t + 1) * Vv + v;
          dst[0 * TV] = z0f;
          dst[1 * TV] = z1f;
          dst[2 * TV] = z2f;
          dst[3 * TV] = z3f;
        }
      }
    }
    __syncthreads();   // barrier B: z state updated before next mm1 reads it

    t += 1;
    if (t >= Tt - 1) break;             // steps t = t0 .. 62
    if (tf[t * Bb + b] >= 0.5f) break;  // next step is teacher-forced -> new chain owns it
  }
}

extern "C" void kernel_launch(void* const* d_in, const int* in_sizes, int n_in,
                              void* d_out, int out_size, void* d_ws, size_t ws_size,
                              hipStream_t stream) {
  const float* h_ptr = (const float*)d_in[0];
  const float* W1    = (const float*)d_in[1];
  const float* b1    = (const float*)d_in[2];
  const float* W2    = (const float*)d_in[3];
  const float* b2    = (const float*)d_in[4];
  const float* tf    = (const float*)d_in[5];
  float* out = (float*)d_out;

  short* a1p = (short*)d_ws;             // 131072 bf16 = 256 KB
  short* a2p = a1p + 131072;             // 131072 bf16 = 256 KB

  prepack_kernel<<<1024, 256, 0, stream>>>(W1, W2, a1p, a2p);
  chain_kernel<<<(Tt - 1) * Bb, 256, 0, stream>>>(h_ptr, b1, b2, tf, a1p, a2p, out);
}

// Round 2
// 444.319 us; speedup vs baseline: 2.1993x; 2.1993x over previous
//
#include <hip/hip_runtime.h>
#include <hip/hip_bf16.h>
#include <math.h>

// ODE Euler solver with teacher forcing — R2: chain-batched MFMA.
// Chains (independent segments between teacher-forcing resets) are extracted
// and counting-sorted by length (desc) by plan_kernel, then packed G=4 per
// block so the 512 KB weight read per step is amortized over 128 columns and
// block-steps drop 4x. fp32 state lives in mm2 accumulator registers across
// steps; z enters mm1 as single bf16.

using bf16x8 = __attribute__((ext_vector_type(8))) short;   // 8 bf16
using f32x4  = __attribute__((ext_vector_type(4))) float;   // 4 fp32 acc

constexpr int Bb = 64, Cc = 256, Tt = 64, Vv = 25, Hh = 512;
constexpr int TV = Tt * Vv;              // 1600
constexpr int G = 4;                     // chains per block
constexpr int NCOL = G * 32;             // 128 columns (V padded 25->32)
constexpr int NT = NCOL / 16;            // 8 n-tiles
constexpr int ZS = 264;                  // z row stride (shorts): 256 + 8 pad
constexpr int US = 264;                  // u-chunk row stride: 256 + 8 pad
constexpr int MAXCH = Bb * (Tt - 1);     // 4032 max chains
constexpr int NBLK = MAXCH / G;          // 1008 blocks

__device__ __forceinline__ short f2bf(float x) {
  union { float f; unsigned u; } v; v.f = x;
  unsigned r = v.u + 0x7FFFu + ((v.u >> 16) & 1u);
  return (short)(r >> 16);
}
__device__ __forceinline__ float fast_tanh(float x) {
  float e = __expf(2.f * x);                       // +inf for large x -> ok
  return 1.f - 2.f * __builtin_amdgcn_rcpf(e + 1.f);
}

// ---- Prepack W1, W2 (fp32 row-major) into MFMA A-fragment order (bf16) ----
// A-frag (16x16x32): lane holds A[m=lane&15][k=(lane>>4)*8+j], j=0..7.
// a1p: A=W1^T (M=H: 32 mt, K=C: 8 kt):  idx ((kt*32+mt)*64+lane)*8+j
// a2p: A=W2^T (M=C: 16 mt, K=H: 16 kt): idx ((kt*16+mt)*64+lane)*8+j
__global__ void prepack_kernel(const float* __restrict__ W1,
                               const float* __restrict__ W2,
                               short* __restrict__ a1p,
                               short* __restrict__ a2p) {
  int idx = blockIdx.x * 256 + threadIdx.x;
  if (idx < 131072) {
    int j = idx & 7, lane = (idx >> 3) & 63, mt = (idx >> 9) & 31, kt = idx >> 14;
    int h = mt * 16 + (lane & 15);
    int c = kt * 32 + (lane >> 4) * 8 + j;
    a1p[idx] = f2bf(W1[c * Hh + h]);
  } else {
    int i2 = idx - 131072;
    int j = i2 & 7, lane = (i2 >> 3) & 63, mt = (i2 >> 9) & 15, kt = i2 >> 13;
    int cm = mt * 16 + (lane & 15);
    int hk = kt * 32 + (lane >> 4) * 8 + j;
    a2p[i2] = f2bf(W2[hk * Cc + cm]);
  }
}

// ---- Plan: extract chains, counting-sort by length descending ----
// sorted[i] = b | (t0<<6) | (len<<12); sentinel = 0 (len==0).
__global__ void plan_kernel(const float* __restrict__ tf, int* __restrict__ sorted) {
  __shared__ int cnt[64];
  __shared__ int ofs[64];
  int tid = threadIdx.x;
  if (tid < 64) cnt[tid] = 0;
  for (int i = tid; i < MAXCH; i += 256) sorted[i] = 0;
  __syncthreads();
  if (tid < Bb) {
    int b = tid, prev = 0;
    for (int t = 1; t <= 62; t++)
      if (tf[t * Bb + b] >= 0.5f) { atomicAdd(&cnt[t - prev], 1); prev = t; }
    atomicAdd(&cnt[63 - prev], 1);
  }
  __syncthreads();
  if (tid == 0) {
    int acc = 0;
    for (int l = 63; l >= 1; l--) { ofs[l] = acc; acc += cnt[l]; }
  }
  __syncthreads();
  if (tid < Bb) {
    int b = tid, prev = 0;
    for (int t = 1; t <= 62; t++) {
      if (tf[t * Bb + b] >= 0.5f) {
        int len = t - prev;
        int p = atomicAdd(&ofs[len], 1);
        sorted[p] = b | (prev << 6) | (len << 12);
        prev = t;
      }
    }
    int len = 63 - prev;
    int p = atomicAdd(&ofs[len], 1);
    sorted[p] = b | (prev << 6) | (len << 12);
  }
}

// ---- Group kernel: 512 threads (8 waves), G=4 chains, N=128 columns ----
__global__ __launch_bounds__(512, 2) void group_kernel(
    const float* __restrict__ hsrc, const float* __restrict__ b1,
    const float* __restrict__ b2,   const short* __restrict__ a1p,
    const short* __restrict__ a2p,  const int* __restrict__ sorted,
    float* __restrict__ out) {
  __shared__ __align__(16) short z_hi[NCOL * ZS];   // 67584 B
  __shared__ __align__(16) short u_ch[NCOL * US];   // 67584 B
  __shared__ int s_meta[G];

  const int tid = threadIdx.x;
  if (tid < G) s_meta[tid] = sorted[blockIdx.x * G + tid];
  __syncthreads();
  const int maxlen = (s_meta[0] >> 12) & 63;   // sorted desc -> first is max
  if (maxlen == 0) return;

  const int lane = tid & 63;
  const int w    = tid >> 6;        // wave 0..7
  const int m16  = lane & 15;
  const int quad = lane >> 4;

  int len4[G];
  #pragma unroll
  for (int j = 0; j < G; j++) len4[j] = (s_meta[j] >> 12) & 63;

  f32x4 acc2[2][NT];                // fp32 master state, persists across steps
  int   obase[2][NT];               // out offset at t = t0 (reg 0)

  // ---- init: z0 = h[b, :, t0, :] (pad cols & dead chains -> 0) ----
  #pragma unroll
  for (int i = 0; i < 2; i++) {
    const int cbase = (w * 2 + i) * 16 + quad * 4;
    #pragma unroll
    for (int nt = 0; nt < NT; nt++) {
      const int j  = nt >> 1;
      const int mj = s_meta[j];
      const int bj = mj & 63, t0 = (mj >> 6) & 63;
      const int v  = (nt & 1) * 16 + m16;
      const bool valid = (len4[j] > 0) && (v < Vv);
      const int hb = ((bj * Cc + cbase) * Tt + t0) * Vv + v;
      f32x4 z;
      #pragma unroll
      for (int r = 0; r < 4; r++) z[r] = valid ? hsrc[hb + r * TV] : 0.f;
      acc2[i][nt] = z;
      obase[i][nt] = hb;            // == out offset at t=t0
      short4 zh;
      zh.x = f2bf(z[0]); zh.y = f2bf(z[1]); zh.z = f2bf(z[2]); zh.w = f2bf(z[3]);
      *(short4*)&z_hi[(nt * 16 + m16) * ZS + cbase] = zh;
      if (valid && t0 == 0) {
        #pragma unroll
        for (int r = 0; r < 4; r++) out[hb + r * TV] = z[r];
      }
    }
  }
  __syncthreads();

  // ---- step loop (lockstep across the G chains) ----
  for (int s = 0; s < maxlen; s++) {
    // acc2 += b2 (start of the additive update)
    #pragma unroll
    for (int i = 0; i < 2; i++) {
      const int cbase = (w * 2 + i) * 16 + quad * 4;
      const float4 bv = *(const float4*)(b2 + cbase);
      #pragma unroll
      for (int nt = 0; nt < NT; nt++) {
        acc2[i][nt][0] += bv.x; acc2[i][nt][1] += bv.y;
        acc2[i][nt][2] += bv.z; acc2[i][nt][3] += bv.w;
      }
    }
    #pragma unroll
    for (int chunk = 0; chunk < 2; chunk++) {
      // -------- mm1 chunk: u[chunk*256 .. +256) = tanh(W1^T z + b1) --------
      f32x4 acc1[2][NT];
      #pragma unroll
      for (int i = 0; i < 2; i++)
        #pragma unroll
        for (int nt = 0; nt < NT; nt++) acc1[i][nt] = (f32x4){0.f, 0.f, 0.f, 0.f};
      #pragma unroll 2
      for (int kt = 0; kt < 8; kt++) {
        bf16x8 af0, af1;
        const short* ab = a1p + ((kt * 32 + chunk * 16 + w * 2) * 64 + lane) * 8;
        af0 = *(const bf16x8*)ab;
        af1 = *(const bf16x8*)(ab + 512);
        const int ko = kt * 32 + quad * 8;
        #pragma unroll
        for (int nt = 0; nt < NT; nt++) {
          bf16x8 bz = *(const bf16x8*)&z_hi[(nt * 16 + m16) * ZS + ko];
          acc1[0][nt] = __builtin_amdgcn_mfma_f32_16x16x32_bf16(af0, bz, acc1[0][nt], 0, 0, 0);
          acc1[1][nt] = __builtin_amdgcn_mfma_f32_16x16x32_bf16(af1, bz, acc1[1][nt], 0, 0, 0);
        }
      }
      __syncthreads();   // previous consumers of u_ch are done
      // u epilogue -> LDS (bf16)
      #pragma unroll
      for (int i = 0; i < 2; i++) {
        const int mtl    = w * 2 + i;                    // 0..15 within chunk
        const int hglob  = (chunk * 16 + mtl) * 16 + quad * 4;
        const int klocal = mtl * 16 + quad * 4;
        const float4 b1v = *(const float4*)(b1 + hglob);
        #pragma unroll
        for (int nt = 0; nt < NT; nt++) {
          short4 up;
          up.x = f2bf(fast_tanh(acc1[i][nt][0] + b1v.x));
          up.y = f2bf(fast_tanh(acc1[i][nt][1] + b1v.y));
          up.z = f2bf(fast_tanh(acc1[i][nt][2] + b1v.z));
          up.w = f2bf(fast_tanh(acc1[i][nt][3] + b1v.w));
          *(short4*)&u_ch[(nt * 16 + m16) * US + klocal] = up;
        }
      }
      __syncthreads();
      // -------- mm2 partial: acc2 += W2[chunk K-range]^T u --------
      #pragma unroll 2
      for (int ktl = 0; ktl < 8; ktl++) {
        bf16x8 af0, af1;
        const short* ab = a2p + (((chunk * 8 + ktl) * 16 + w * 2) * 64 + lane) * 8;
        af0 = *(const bf16x8*)ab;
        af1 = *(const bf16x8*)(ab + 512);
        const int ko = ktl * 32 + quad * 8;
        #pragma unroll
        for (int nt = 0; nt < NT; nt++) {
          bf16x8 bu = *(const bf16x8*)&u_ch[(nt * 16 + m16) * US + ko];
          acc2[0][nt] = __builtin_amdgcn_mfma_f32_16x16x32_bf16(af0, bu, acc2[0][nt], 0, 0, 0);
          acc2[1][nt] = __builtin_amdgcn_mfma_f32_16x16x32_bf16(af1, bu, acc2[1][nt], 0, 0, 0);
        }
      }
    } // chunks
    // ---- z epilogue: acc2 is z_new; refresh LDS bf16, store alive cols ----
    #pragma unroll
    for (int i = 0; i < 2; i++) {
      const int cbase = (w * 2 + i) * 16 + quad * 4;
      #pragma unroll
      for (int nt = 0; nt < NT; nt++) {
        short4 zh;
        zh.x = f2bf(acc2[i][nt][0]); zh.y = f2bf(acc2[i][nt][1]);
        zh.z = f2bf(acc2[i][nt][2]); zh.w = f2bf(acc2[i][nt][3]);
        *(short4*)&z_hi[(nt * 16 + m16) * ZS + cbase] = zh;
        const int v = (nt & 1) * 16 + m16;
        if (v < Vv && s < len4[nt >> 1]) {
          const int o = obase[i][nt] + (s + 1) * Vv;
          out[o]          = acc2[i][nt][0];
          out[o + TV]     = acc2[i][nt][1];
          out[o + 2 * TV] = acc2[i][nt][2];
          out[o + 3 * TV] = acc2[i][nt][3];
        }
      }
    }
    __syncthreads();
  }
}

extern "C" void kernel_launch(void* const* d_in, const int* in_sizes, int n_in,
                              void* d_out, int out_size, void* d_ws, size_t ws_size,
                              hipStream_t stream) {
  const float* h_ptr = (const float*)d_in[0];
  const float* W1    = (const float*)d_in[1];
  const float* b1    = (const float*)d_in[2];
  const float* W2    = (const float*)d_in[3];
  const float* b2    = (const float*)d_in[4];
  const float* tf    = (const float*)d_in[5];
  float* out = (float*)d_out;

  short* a1p  = (short*)d_ws;            // 256 KB
  short* a2p  = a1p + 131072;            // 256 KB
  int* sorted = (int*)(a2p + 131072);    // 16 KB

  prepack_kernel<<<1024, 256, 0, stream>>>(W1, W2, a1p, a2p);
  plan_kernel<<<1, 256, 0, stream>>>(tf, sorted);
  group_kernel<<<NBLK, 512, 0, stream>>>(h_ptr, b1, b2, a1p, a2p, sorted, out);
}

// Round 3
// 366.206 us; speedup vs baseline: 2.6685x; 1.2133x over previous
//
#include <hip/hip_runtime.h>
#include <hip/hip_bf16.h>
#include <math.h>

// ODE Euler solver with teacher forcing — R3.
// Changes vs R2:
//  * LDS holds z and u in MFMA B-fragment order -> every ds_read_b128 is
//    lane-sequential (zero bank conflicts), epilogue writes are contiguous.
//  * Length-adaptive grouping: chains len>=5 run solo (N=32, shortest step
//    latency -> short critical path), len 3-4 in pairs, len<=2 in quads
//    (weight-stream amortization for the bulk).
//  * prepack+plan fused into one launch.

using bf16x8 = __attribute__((ext_vector_type(8))) short;   // 8 bf16
using f32x4  = __attribute__((ext_vector_type(4))) float;   // 4 fp32 acc

constexpr int Bb = 64, Cc = 256, Tt = 64, Vv = 25, Hh = 512;
constexpr int TV = Tt * Vv;              // 1600
constexpr int NCOL = 128;                // max columns (4 chains x 32)
constexpr int NT = NCOL / 16;            // 8 n-tiles max
constexpr int MAXCH = Bb * (Tt - 1);     // 4032
constexpr int NGRID = 2496;              // >= worst-case group count

__device__ __forceinline__ short f2bf(float x) {
  union { float f; unsigned u; } v; v.f = x;
  unsigned r = v.u + 0x7FFFu + ((v.u >> 16) & 1u);
  return (short)(r >> 16);
}
__device__ __forceinline__ float fast_tanh(float x) {
  float e = __expf(2.f * x);
  return 1.f - 2.f * __builtin_amdgcn_rcpf(e + 1.f);
}

// ---- fused prepack (blocks 0..1023) + plan (block 1024) ----
// A-frag (16x16x32): lane holds A[m=lane&15][k=(lane>>4)*8+j].
// a1p: A=W1^T (M=H: 32 mt, K=C: 8 kt):  idx ((kt*32+mt)*64+lane)*8+j
// a2p: A=W2^T (M=C: 16 mt, K=H: 16 kt): idx ((kt*16+mt)*64+lane)*8+j
// plan: chains counting-sorted by len desc; hdr = {n1, g2, g4, q0}.
__global__ void prep_kernel(const float* __restrict__ W1,
                            const float* __restrict__ W2,
                            const float* __restrict__ tf,
                            short* __restrict__ a1p,
                            short* __restrict__ a2p,
                            int* __restrict__ sorted,
                            int* __restrict__ hdr) {
  if (blockIdx.x < 1024) {
    int idx = blockIdx.x * 256 + threadIdx.x;
    if (idx < 131072) {
      int j = idx & 7, lane = (idx >> 3) & 63, mt = (idx >> 9) & 31, kt = idx >> 14;
      int h = mt * 16 + (lane & 15);
      int c = kt * 32 + (lane >> 4) * 8 + j;
      a1p[idx] = f2bf(W1[c * Hh + h]);
    } else {
      int i2 = idx - 131072;
      int j = i2 & 7, lane = (i2 >> 3) & 63, mt = (i2 >> 9) & 15, kt = i2 >> 13;
      int cm = mt * 16 + (lane & 15);
      int hk = kt * 32 + (lane >> 4) * 8 + j;
      a2p[i2] = f2bf(W2[hk * Cc + cm]);
    }
    return;
  }
  // ---- planning block ----
  __shared__ int cnt[64];
  __shared__ int ofs[64];
  int tid = threadIdx.x;
  if (tid < 64) cnt[tid] = 0;
  for (int i = tid; i < MAXCH; i += 256) sorted[i] = 0;
  __syncthreads();
  if (tid < Bb) {
    int b = tid, prev = 0;
    for (int t = 1; t <= 62; t++)
      if (tf[t * Bb + b] >= 0.5f) { atomicAdd(&cnt[t - prev], 1); prev = t; }
    atomicAdd(&cnt[63 - prev], 1);
  }
  __syncthreads();
  if (tid == 0) {
    int acc = 0;
    for (int l = 63; l >= 1; l--) { ofs[l] = acc; acc += cnt[l]; }
    int n1 = 0;
    for (int l = 5; l <= 63; l++) n1 += cnt[l];
    int n2 = cnt[3] + cnt[4];
    int nch = acc;
    int g2 = (n2 + 1) >> 1;
    int q0 = n1 + 2 * g2;
    int rem = nch - q0; if (rem < 0) rem = 0;
    int g4 = (rem + 3) >> 2;
    hdr[0] = n1; hdr[1] = g2; hdr[2] = g4; hdr[3] = q0;
  }
  __syncthreads();
  if (tid < Bb) {
    int b = tid, prev = 0;
    for (int t = 1; t <= 62; t++) {
      if (tf[t * Bb + b] >= 0.5f) {
        int len = t - prev;
        int p = atomicAdd(&ofs[len], 1);
        sorted[p] = b | (prev << 6) | (len << 12);
        prev = t;
      }
    }
    int len = 63 - prev;
    int p = atomicAdd(&ofs[len], 1);
    sorted[p] = b | (prev << 6) | (len << 12);
  }
}

// ---- Group kernel: 512 threads (8 waves), adaptive G in {1,2,4} ----
// LDS B-frag order: elem(k,n) at ((ktile*NT + nt)*64 + (n&15) + 16*((k&31)>>3))*8 + (k&7)
__global__ __launch_bounds__(512, 2) void group_kernel(
    const float* __restrict__ hsrc, const float* __restrict__ b1,
    const float* __restrict__ b2,   const short* __restrict__ a1p,
    const short* __restrict__ a2p,  const int* __restrict__ sorted,
    const int* __restrict__ hdr,    float* __restrict__ out) {
  __shared__ __align__(16) short zB[8 * NT * 64 * 8];   // 64 KB (K=256)
  __shared__ __align__(16) short uB[8 * NT * 64 * 8];   // 64 KB (K-chunk=256)
  __shared__ int s_meta[4];

  const int n1 = hdr[0], g2 = hdr[1], g4 = hdr[2], q0 = hdr[3];
  const int bi = blockIdx.x;
  int start, gsz;
  if (bi < n1)                { start = bi;                        gsz = 1; }
  else if (bi < n1 + g2)      { start = n1 + (bi - n1) * 2;        gsz = 2; }
  else if (bi < n1 + g2 + g4) { start = q0 + (bi - n1 - g2) * 4;   gsz = 4; }
  else return;

  const int tid = threadIdx.x;
  if (tid < 4) s_meta[tid] = (tid < gsz) ? sorted[start + tid] : 0;
  __syncthreads();
  const int maxlen = (s_meta[0] >> 12) & 63;
  const int ntMax  = gsz * 2;

  const int lane = tid & 63;
  const int w    = tid >> 6;
  const int m16  = lane & 15;
  const int quad = lane >> 4;

  int len4[4];
  #pragma unroll
  for (int j = 0; j < 4; j++) len4[j] = (s_meta[j] >> 12) & 63;

  f32x4 acc2[2][NT];                // fp32 master state across steps
  int   obase[2][NT];

  // ---- init: z0 = h[b,:,t0,:]; write zB in B-frag order ----
  #pragma unroll
  for (int i = 0; i < 2; i++) {
    const int cbase = (w * 2 + i) * 16 + quad * 4;    // 0..255, mult of 4
    const int ktz = cbase >> 5;
    const int gq  = (cbase >> 3) & 3;
    const int j0  = cbase & 7;                        // 0 or 4
    #pragma unroll
    for (int nt = 0; nt < NT; nt++) {
      if (nt >= ntMax) break;
      const int j  = nt >> 1;
      const int mj = s_meta[j];
      const int bj = mj & 63, t0 = (mj >> 6) & 63;
      const int v  = (nt & 1) * 16 + m16;
      const bool valid = (len4[j] > 0) && (v < Vv);
      const int hb = ((bj * Cc + cbase) * Tt + t0) * Vv + v;
      f32x4 z;
      #pragma unroll
      for (int r = 0; r < 4; r++) z[r] = valid ? hsrc[hb + r * TV] : 0.f;
      acc2[i][nt] = z;
      obase[i][nt] = hb;
      short4 zh;
      zh.x = f2bf(z[0]); zh.y = f2bf(z[1]); zh.z = f2bf(z[2]); zh.w = f2bf(z[3]);
      *(short4*)&zB[((ktz * NT + nt) * 64 + m16 + 16 * gq) * 8 + j0] = zh;
      if (valid && t0 == 0) {
        #pragma unroll
        for (int r = 0; r < 4; r++) out[hb + r * TV] = z[r];
      }
    }
  }
  __syncthreads();

  // ---- step loop ----
  for (int s = 0; s < maxlen; s++) {
    #pragma unroll
    for (int i = 0; i < 2; i++) {
      const int cbase = (w * 2 + i) * 16 + quad * 4;
      const float4 bv = *(const float4*)(b2 + cbase);
      #pragma unroll
      for (int nt = 0; nt < NT; nt++) {
        if (nt >= ntMax) break;
        acc2[i][nt][0] += bv.x; acc2[i][nt][1] += bv.y;
        acc2[i][nt][2] += bv.z; acc2[i][nt][3] += bv.w;
      }
    }
    #pragma unroll
    for (int chunk = 0; chunk < 2; chunk++) {
      // ---- mm1 chunk: u[chunk*256..+256) = tanh(W1^T z + b1) ----
      f32x4 acc1[2][NT];
      #pragma unroll
      for (int i = 0; i < 2; i++)
        #pragma unroll
        for (int nt = 0; nt < NT; nt++) acc1[i][nt] = (f32x4){0.f, 0.f, 0.f, 0.f};
      #pragma unroll 2
      for (int kt = 0; kt < 8; kt++) {
        const short* ab = a1p + ((kt * 32 + chunk * 16 + w * 2) * 64 + lane) * 8;
        bf16x8 af0 = *(const bf16x8*)ab;
        bf16x8 af1 = *(const bf16x8*)(ab + 512);
        #pragma unroll
        for (int nt = 0; nt < NT; nt++) {
          if (nt >= ntMax) break;
          bf16x8 bz = *(const bf16x8*)&zB[((kt * NT + nt) * 64 + lane) * 8];
          acc1[0][nt] = __builtin_amdgcn_mfma_f32_16x16x32_bf16(af0, bz, acc1[0][nt], 0, 0, 0);
          acc1[1][nt] = __builtin_amdgcn_mfma_f32_16x16x32_bf16(af1, bz, acc1[1][nt], 0, 0, 0);
        }
      }
      __syncthreads();   // previous consumers of uB done
      // u epilogue -> uB (B-frag order, chunk-local K)
      #pragma unroll
      for (int i = 0; i < 2; i++) {
        const int mtl   = w * 2 + i;                   // 0..15 (chunk-local mtile)
        const int hl    = mtl * 16 + quad * 4;         // chunk-local h, mult of 4
        const int hglob = chunk * 256 + hl;
        const int ktl = hl >> 5;
        const int gq  = (hl >> 3) & 3;
        const int j0  = hl & 7;
        const float4 b1v = *(const float4*)(b1 + hglob);
        #pragma unroll
        for (int nt = 0; nt < NT; nt++) {
          if (nt >= ntMax) break;
          short4 up;
          up.x = f2bf(fast_tanh(acc1[i][nt][0] + b1v.x));
          up.y = f2bf(fast_tanh(acc1[i][nt][1] + b1v.y));
          up.z = f2bf(fast_tanh(acc1[i][nt][2] + b1v.z));
          up.w = f2bf(fast_tanh(acc1[i][nt][3] + b1v.w));
          *(short4*)&uB[((ktl * NT + nt) * 64 + m16 + 16 * gq) * 8 + j0] = up;
        }
      }
      __syncthreads();
      // ---- mm2 partial: acc2 += W2[chunk]^T u ----
      #pragma unroll 2
      for (int ktl = 0; ktl < 8; ktl++) {
        const short* ab = a2p + (((chunk * 8 + ktl) * 16 + w * 2) * 64 + lane) * 8;
        bf16x8 af0 = *(const bf16x8*)ab;
        bf16x8 af1 = *(const bf16x8*)(ab + 512);
        #pragma unroll
        for (int nt = 0; nt < NT; nt++) {
          if (nt >= ntMax) break;
          bf16x8 bu = *(const bf16x8*)&uB[((ktl * NT + nt) * 64 + lane) * 8];
          acc2[0][nt] = __builtin_amdgcn_mfma_f32_16x16x32_bf16(af0, bu, acc2[0][nt], 0, 0, 0);
          acc2[1][nt] = __builtin_amdgcn_mfma_f32_16x16x32_bf16(af1, bu, acc2[1][nt], 0, 0, 0);
        }
      }
    } // chunks
    // ---- z epilogue: refresh zB, store alive cols ----
    #pragma unroll
    for (int i = 0; i < 2; i++) {
      const int cbase = (w * 2 + i) * 16 + quad * 4;
      const int ktz = cbase >> 5;
      const int gq  = (cbase >> 3) & 3;
      const int j0  = cbase & 7;
      #pragma unroll
      for (int nt = 0; nt < NT; nt++) {
        if (nt >= ntMax) break;
        short4 zh;
        zh.x = f2bf(acc2[i][nt][0]); zh.y = f2bf(acc2[i][nt][1]);
        zh.z = f2bf(acc2[i][nt][2]); zh.w = f2bf(acc2[i][nt][3]);
        *(short4*)&zB[((ktz * NT + nt) * 64 + m16 + 16 * gq) * 8 + j0] = zh;
        const int v = (nt & 1) * 16 + m16;
        if (v < Vv && s < len4[nt >> 1]) {
          const int o = obase[i][nt] + (s + 1) * Vv;
          out[o]          = acc2[i][nt][0];
          out[o + TV]     = acc2[i][nt][1];
          out[o + 2 * TV] = acc2[i][nt][2];
          out[o + 3 * TV] = acc2[i][nt][3];
        }
      }
    }
    __syncthreads();
  }
}

extern "C" void kernel_launch(void* const* d_in, const int* in_sizes, int n_in,
                              void* d_out, int out_size, void* d_ws, size_t ws_size,
                              hipStream_t stream) {
  const float* h_ptr = (const float*)d_in[0];
  const float* W1    = (const float*)d_in[1];
  const float* b1    = (const float*)d_in[2];
  const float* W2    = (const float*)d_in[3];
  const float* b2    = (const float*)d_in[4];
  const float* tf    = (const float*)d_in[5];
  float* out = (float*)d_out;

  short* a1p  = (short*)d_ws;            // 256 KB
  short* a2p  = a1p + 131072;            // 256 KB
  int* sorted = (int*)(a2p + 131072);    // 16 KB
  int* hdr    = sorted + MAXCH;          // 16 B

  prep_kernel<<<1025, 256, 0, stream>>>(W1, W2, tf, a1p, a2p, sorted, hdr);
  group_kernel<<<NGRID, 512, 0, stream>>>(h_ptr, b1, b2, a1p, a2p, sorted, hdr, out);
}